// Round 7
// baseline (74.031 us; speedup 1.0000x reference)
//
#include <hip/hip_runtime.h>

#define HWN 9216   // 96*96
#define SCALE 0.1767766952966369f

static __device__ __forceinline__ float rcp_fast(float x) {
  return __builtin_amdgcn_rcpf(x);
}
static __device__ __forceinline__ float rl_f(float x, int l) {
  return __int_as_float(__builtin_amdgcn_readlane(__float_as_int(x), l));
}
template <int C>
static __device__ __forceinline__ float dpps(float x) {  // sum step (0-fill)
  return x + __int_as_float(__builtin_amdgcn_update_dpp(
                 0, __float_as_int(x), C, 0xf, 0xf, true));
}
static __device__ __forceinline__ float wave_sum63(float x) {
  x = dpps<0x111>(x); x = dpps<0x112>(x); x = dpps<0x114>(x);
  x = dpps<0x118>(x); x = dpps<0x142>(x); x = dpps<0x143>(x);
  return x;  // lane 63 holds the 64-lane total
}

// ---------------- Kernel 0: weight prep ----------------
// w_vpI[r][2c+0] = sum_{d<32}  w_v[r][d]    * w_proj[d][c]   (head-0 half)
// w_vpI[r][2c+1] = sum_{d<32}  w_v[r][d+32] * w_proj[d+32][c](head-1 half)
extern "C" __global__ void __launch_bounds__(256) prep_kernel(
    const float* __restrict__ w_v, const float* __restrict__ w_proj,
    float* __restrict__ w_vpI) {
  const int idx = blockIdx.x * 256 + threadIdx.x;  // 16 blocks -> 4096
  const int r = idx >> 6, c = idx & 63;
  float s0 = 0.f, s1 = 0.f;
#pragma unroll 8
  for (int d = 0; d < 32; ++d) {
    s0 += w_v[r * 64 + d] * w_proj[d * 64 + c];
    s1 += w_v[r * 64 + 32 + d] * w_proj[(32 + d) * 64 + c];
  }
  w_vpI[r * 128 + 2 * c] = s0;
  w_vpI[r * 128 + 2 * c + 1] = s1;
}

// ---------------- Kernel 1: QKV' projection (no LDS) ----------------
// Grid 1152 = 288 px-blocks x 4 col-blocks. qkv row = 256 floats/pixel:
// [ q*SCALE (64) | k (64) | vI (128: v0',v1' interleaved per channel) ]
extern "C" __global__ void __launch_bounds__(256) qkv_proj_kernel(
    const float* __restrict__ x, const float* __restrict__ w_qk,
    const float* __restrict__ w_vpI, float* __restrict__ qkv) {
  const int t = threadIdx.x;
  const int bid = blockIdx.x;
  const int cb = bid & 3;
  const int pxblk = bid >> 2;
  const int b = (pxblk >= 144) ? 1 : 0;
  const int p0 = (pxblk - b * 144) * 64;
  const int pxg = t >> 4, cg = t & 15;
  const float* xb = x + b * (64 * HWN) + p0 + pxg * 4;
  // cb0 -> w_qk cols 0..63; cb1 -> w_qk cols 64..127;
  // cb2 -> w_vpI cols 0..63; cb3 -> w_vpI cols 64..127. All ld = 128.
  const float* wsrc =
      ((cb < 2) ? w_qk : w_vpI) + (cb & 1) * 64 + cg * 4;
  float acc[4][4];
#pragma unroll
  for (int p = 0; p < 4; ++p)
#pragma unroll
    for (int c = 0; c < 4; ++c) acc[p][c] = 0.f;
#pragma unroll 8
  for (int d = 0; d < 64; ++d) {
    const float4 av = *(const float4*)(xb + d * HWN);
    const float4 wv = *(const float4*)(wsrc + d * 128);
    const float aa[4] = {av.x, av.y, av.z, av.w};
    const float ww[4] = {wv.x, wv.y, wv.z, wv.w};
#pragma unroll
    for (int p = 0; p < 4; ++p)
#pragma unroll
      for (int c = 0; c < 4; ++c) acc[p][c] += aa[p] * ww[c];
  }
  const float sc = (cb == 0) ? SCALE : 1.f;
  const int pixbase = b * HWN + p0 + pxg * 4;
#pragma unroll
  for (int p = 0; p < 4; ++p) {
    *(float4*)&qkv[(pixbase + p) * 256 + cb * 64 + cg * 4] =
        make_float4(acc[p][0] * sc, acc[p][1] * sc, acc[p][2] * sc,
                    acc[p][3] * sc);
  }
}

// ---------------- Kernel 2: fused attention ----------------
// WG = 512 thr = 8 waves; 2x4 pixel tile. Wave = pixel. One barrier.
// QK: lane = neighbor, k row-major b64, q broadcast via readlane.
// PV: lane = out channel, vI b64 (both heads), weights via readlane.
extern "C" __global__ void __launch_bounds__(512, 4) attn_fused_kernel(
    const float* __restrict__ qkv, const float* __restrict__ sims,
    const float* __restrict__ b_proj, float* __restrict__ out) {
  __shared__ __align__(16) float vI[80 * 128];  // 40960 B
  __shared__ __align__(16) float kRM[80 * 66];  // 21120 B (2-float pad/cell)
  __shared__ float simsL[80 * 9];               // 2880 B   total 64960 B

  const int t = threadIdx.x;
  const int lane = t & 63;
  const int wvv = t >> 6;

  int wg = blockIdx.x;  // 2304 = 2 * 48 * 24
  const int bb = (wg >= 1152) ? 1 : 0;
  wg -= bb * 1152;
  const int i0 = (wg / 24) * 2;
  const int j0 = (wg % 24) * 4;
  const int rstart0 = max(min(i0 - 3, 88), 0);  // 8 staged rows
  const int cstart0 = max(min(j0 - 3, 86), 0);  // 10 staged cols

  const float* qkvb = qkv + bb * (HWN * 256);
  const float bp = b_proj[lane];

  // ---- stage k rows (flat b64 over padded 80x66 region) ----
  for (int u = t; u < 2640; u += 512) {
    const int f = u * 2;
    const int cell = f / 66;
    const int e = f - cell * 66;
    const int pix = (rstart0 + cell / 10) * 96 + cstart0 + (cell - (cell / 10) * 10);
    const int e2 = min(e, 62);  // e==64 -> pad pair, harmless dup
    *(float2*)&kRM[f] = *(const float2*)(qkvb + pix * 256 + 64 + e2);
  }
  // ---- stage vI (flat b128 over 80x128 region) ----
  for (int u = t; u < 2560; u += 512) {
    const int f = u * 4;
    const int cell = f >> 7;
    const int e = f & 127;
    const int pix = (rstart0 + cell / 10) * 96 + cstart0 + (cell - (cell / 10) * 10);
    *(float4*)&vI[f] = *(const float4*)(qkvb + pix * 256 + 128 + e);
  }
  // ---- stage sims (+eps), superpixel index computed inline ----
  {
    const int si = i0 >> 3, sj = j0 >> 3;
    const float* simsb = sims + bb * (HWN * 144);
    for (int el = t; el < 720; el += 512) {
      const int cell = el / 9;
      const int s = el - cell * 9;
      const int pix = (rstart0 + cell / 10) * 96 + cstart0 + (cell - (cell / 10) * 10);
      const int sa = s / 3, sb2 = s - sa * 3;
      const int sr = min(max(si + sa - 1, 0), 11);
      const int sc = min(max(sj + sb2 - 1, 0), 11);
      simsL[cell * 9 + s] = simsb[pix * 144 + sr * 12 + sc] + 1e-12f;
    }
  }
  // ---- q for this wave's pixel (register; broadcast via readlane) ----
  const int i = i0 + (wvv >> 2), j = j0 + (wvv & 3);
  const float qv = qkvb[(i * 96 + j) * 256 + lane];  // pre-scaled q
  __syncthreads();

  // ---- per-wave: lane owns neighbor nn ----
  const int dr = max(min(i - 3, 89), 0) - rstart0;  // 0..1
  const int dc = max(min(j - 3, 89), 0) - cstart0;  // 0..3
  const int nn = min(lane, 48);
  const int cell = (dr + nn / 7) * 10 + (dc + nn % 7);

  // QK: 32 x b64 k reads (all 64 dims); head0 = dims 0..31, head1 = 32..63
  const float* kp = &kRM[cell * 66];
  float a0 = 0.f, a1 = 0.f;
#pragma unroll
  for (int g = 0; g < 32; ++g) {
    const float2 k2 = *(const float2*)(kp + 2 * g);
    const float qlo = rl_f(qv, 2 * g);
    const float qhi = rl_f(qv, 2 * g + 1);
    if (g < 16) a0 += qlo * k2.x + qhi * k2.y;
    else        a1 += qlo * k2.x + qhi * k2.y;
  }
  // softmax without max-subtraction (logits are O(+-6); f32 has headroom)
  const float e0 = (lane < 49) ? __expf(a0) : 0.f;
  const float e1 = (lane < 49) ? __expf(a1) : 0.f;

  // Z_s = sum_n (Pj+eps)*e per head; combine weights
  const float* spL = &simsL[cell * 9];
  float tv[9];
#pragma unroll
  for (int s = 0; s < 9; ++s) tv[s] = spL[s];
  const float* cpc = &simsL[((i - rstart0) * 10 + (j - cstart0)) * 9];
  float w0 = 0.f, w1 = 0.f;
#pragma unroll
  for (int s = 0; s < 9; ++s) {
    const float Z0 = rl_f(wave_sum63(tv[s] * e0), 63);
    const float Z1 = rl_f(wave_sum63(tv[s] * e1), 63);
    const float pis = cpc[s];
    w0 += tv[s] * (pis * rcp_fast(Z0));
    w1 += tv[s] * (pis * rcp_fast(Z1));
  }
  w0 *= e0;  // wcomb[h0][n=lane]
  w1 *= e1;  // wcomb[h1][n=lane]

  // PV: lane = out channel; b64 gets (v0'[ch], v1'[ch]); weights via readlane
  const float* vbase = &vI[(dr * 10 + dc) * 128 + lane * 2];
  float o0 = bp, o1 = 0.f, o2 = 0.f, o3 = 0.f;
#pragma unroll
  for (int n = 0; n < 49; ++n) {
    const int off = ((n / 7) * 10 + (n % 7)) * 128;
    const float2 v2 = *(const float2*)(vbase + off);
    const float wa = rl_f(w0, n);
    const float wb = rl_f(w1, n);
    if (n & 1) { o2 += wa * v2.x; o3 += wb * v2.y; }
    else       { o0 += wa * v2.x; o1 += wb * v2.y; }
  }
  out[(bb * 64 + lane) * HWN + i * 96 + j] = (o0 + o2) + (o1 + o3);
}

extern "C" void kernel_launch(void* const* d_in, const int* in_sizes, int n_in,
                              void* d_out, int out_size, void* d_ws, size_t ws_size,
                              hipStream_t stream) {
  const float* x      = (const float*)d_in[0];
  const float* sims   = (const float*)d_in[1];
  const float* w_qk   = (const float*)d_in[2];
  const float* w_v    = (const float*)d_in[3];
  const float* w_proj = (const float*)d_in[4];
  const float* b_proj = (const float*)d_in[5];
  float* outp  = (float*)d_out;
  float* qkv   = (float*)d_ws;                 // 18432*256*4 = 18.9 MB
  float* w_vpI = qkv + (size_t)18432 * 256;    // 8192 floats

  prep_kernel<<<dim3(16), dim3(256), 0, stream>>>(w_v, w_proj, w_vpI);
  qkv_proj_kernel<<<dim3(1152), dim3(256), 0, stream>>>(x, w_qk, w_vpI, qkv);
  attn_fused_kernel<<<dim3(2304), dim3(512), 0, stream>>>(qkv, sims, b_proj,
                                                          outp);
}

// Round 8
// 65.179 us; speedup vs baseline: 1.1358x; 1.1358x over previous
//
#include <hip/hip_runtime.h>

#define HWN 9216   // 96*96
#define SCALE 0.1767766952966369f

static __device__ __forceinline__ float rcp_fast(float x) {
  return __builtin_amdgcn_rcpf(x);
}
static __device__ __forceinline__ float rl_f(float x, int l) {
  return __int_as_float(__builtin_amdgcn_readlane(__float_as_int(x), l));
}
template <int C>
static __device__ __forceinline__ float dpps(float x) {  // sum step (0-fill)
  return x + __int_as_float(__builtin_amdgcn_update_dpp(
                 0, __float_as_int(x), C, 0xf, 0xf, true));
}
static __device__ __forceinline__ float wave_sum63(float x) {
  x = dpps<0x111>(x); x = dpps<0x112>(x); x = dpps<0x114>(x);
  x = dpps<0x118>(x); x = dpps<0x142>(x); x = dpps<0x143>(x);
  return x;  // lane 63 holds the 64-lane total
}

// ---------------- Kernel 0: weight prep ----------------
// w_vpI[r][2c+0] = sum_{d<32} w_v[r][d]    * w_proj[d][c]      (head-0 half)
// w_vpI[r][2c+1] = sum_{d<32} w_v[r][d+32] * w_proj[d+32][c]   (head-1 half)
extern "C" __global__ void __launch_bounds__(256) prep_kernel(
    const float* __restrict__ w_v, const float* __restrict__ w_proj,
    float* __restrict__ w_vpI) {
  const int idx = blockIdx.x * 256 + threadIdx.x;  // 16 blocks -> 4096
  const int r = idx >> 6, c = idx & 63;
  float s0 = 0.f, s1 = 0.f;
#pragma unroll 8
  for (int d = 0; d < 32; ++d) {
    s0 += w_v[r * 64 + d] * w_proj[d * 64 + c];
    s1 += w_v[r * 64 + 32 + d] * w_proj[(32 + d) * 64 + c];
  }
  w_vpI[r * 128 + 2 * c] = s0;
  w_vpI[r * 128 + 2 * c + 1] = s1;
}

// ---------------- Kernel 1: QKV' projection (LDS-staged) ----------------
// Grid 1152 = 288 px-blocks x 4 col-blocks. qkv row = 256 floats/pixel:
// [ q*SCALE (64) | k (64) | vI (128: v0',v1' interleaved per channel) ]
extern "C" __global__ void __launch_bounds__(256) qkv_proj_kernel(
    const float* __restrict__ x, const float* __restrict__ w_qk,
    const float* __restrict__ w_vpI, float* __restrict__ qkv) {
  __shared__ __align__(16) float A[64 * 64];   // [d][px]
  __shared__ __align__(16) float Wl[64 * 64];  // [d][c]
  const int t = threadIdx.x;
  const int bid = blockIdx.x;
  const int cb = bid & 3;
  const int pxblk = bid >> 2;
  const int b = (pxblk >= 144) ? 1 : 0;
  const int p0 = (pxblk - b * 144) * 64;
  const float* xb = x + b * (64 * HWN) + p0;
  // cb0 -> w_qk cols 0..63; cb1 -> w_qk cols 64..127;
  // cb2 -> w_vpI cols 0..63; cb3 -> w_vpI cols 64..127. ld = 128 for both.
  const float* wsrc = ((cb < 2) ? w_qk : w_vpI) + (cb & 1) * 64;
#pragma unroll
  for (int rep = 0; rep < 16; ++rep) {
    const int idx = rep * 256 + t;
    A[idx] = xb[(idx >> 6) * HWN + (idx & 63)];
    Wl[idx] = wsrc[(idx >> 6) * 128 + (idx & 63)];
  }
  __syncthreads();
  const int pxg = t >> 4, cg = t & 15;
  float acc[4][4];
#pragma unroll
  for (int p = 0; p < 4; ++p)
#pragma unroll
    for (int c = 0; c < 4; ++c) acc[p][c] = 0.f;
#pragma unroll 8
  for (int d = 0; d < 64; ++d) {
    const float4 av = *(const float4*)&A[d * 64 + pxg * 4];
    const float4 wv = *(const float4*)&Wl[d * 64 + cg * 4];
    const float aa[4] = {av.x, av.y, av.z, av.w};
    const float ww[4] = {wv.x, wv.y, wv.z, wv.w};
#pragma unroll
    for (int p = 0; p < 4; ++p)
#pragma unroll
      for (int c = 0; c < 4; ++c) acc[p][c] += aa[p] * ww[c];
  }
  const float sc = (cb == 0) ? SCALE : 1.f;
  const int pixbase = b * HWN + p0 + pxg * 4;
#pragma unroll
  for (int p = 0; p < 4; ++p) {
    *(float4*)&qkv[(pixbase + p) * 256 + cb * 64 + cg * 4] =
        make_float4(acc[p][0] * sc, acc[p][1] * sc, acc[p][2] * sc,
                    acc[p][3] * sc);
  }
}

// ---------------- Kernel 2: fused attention ----------------
// WG = 512 thr = 8 waves; 2x4 pixel tile. Wave = pixel. One barrier.
// QK: lane = neighbor, kT b32 imm-offset reads, q via uniform b128.
// PV: lane = out channel, v' b64 from GLOBAL (L2), weights via readlane.
extern "C" __global__ void __launch_bounds__(512, 6) attn_fused_kernel(
    const float* __restrict__ qkv, const float* __restrict__ sims,
    const float* __restrict__ b_proj, float* __restrict__ out) {
  __shared__ __align__(16) float kT[64 * 81];  // 20736 B, [d][cell] pad 81
  __shared__ float simsL[80 * 9];              // 2880 B
  __shared__ __align__(16) float qL[8 * 64];   // 2048 B   total 25664 B

  const int t = threadIdx.x;
  const int lane = t & 63;
  const int wvv = t >> 6;

  int wg = blockIdx.x;  // 2304 = 2 * 48 * 24
  const int bb = (wg >= 1152) ? 1 : 0;
  wg -= bb * 1152;
  const int i0 = (wg / 24) * 2;
  const int j0 = (wg % 24) * 4;
  const int rstart0 = max(min(i0 - 3, 88), 0);  // 8 staged rows
  const int cstart0 = max(min(j0 - 3, 86), 0);  // 10 staged cols

  const float* qkvb = qkv + bb * (HWN * 256);
  const float bp = b_proj[lane];

  // ---- stage k transposed: wave wvv stages halo row wvv (10 cells) ----
  {
    const float* src =
        qkvb + ((rstart0 + wvv) * 96 + cstart0) * 256 + 64 + lane;
#pragma unroll
    for (int kk = 0; kk < 10; ++kk) {
      kT[lane * 81 + (wvv * 10 + kk)] = src[kk * 256];
    }
  }
  // ---- stage q (pre-scaled) ----
  const int i = i0 + (wvv >> 2), j = j0 + (wvv & 3);
  qL[wvv * 64 + lane] = qkvb[(i * 96 + j) * 256 + lane];
  // ---- stage sims (+eps) ----
  {
    const int si = i0 >> 3, sj = j0 >> 3;
    const float* simsb = sims + bb * (HWN * 144);
    for (int el = t; el < 720; el += 512) {
      const int cell = el / 9;
      const int s = el - cell * 9;
      const int pix =
          (rstart0 + cell / 10) * 96 + cstart0 + (cell - (cell / 10) * 10);
      const int sa = s / 3, sb2 = s - sa * 3;
      const int sr = min(max(si + sa - 1, 0), 11);
      const int sc = min(max(sj + sb2 - 1, 0), 11);
      simsL[cell * 9 + s] = simsb[pix * 144 + sr * 12 + sc] + 1e-12f;
    }
  }
  __syncthreads();

  // ---- per-wave: lane owns neighbor nn ----
  const int dr = max(min(i - 3, 89), 0) - rstart0;  // 0..1
  const int dc = max(min(j - 3, 89), 0) - cstart0;  // 0..3
  const int nn = min(lane, 48);
  const int cell = (dr + nn / 7) * 10 + (dc + nn % 7);

  // QK: 64 conflict-free b32 k-reads (imm offsets), q uniform b128
  const float* qp = &qL[wvv * 64];
  const float* kp = &kT[cell];
  float a0 = 0.f, a1 = 0.f;
#pragma unroll
  for (int g = 0; g < 8; ++g) {
    const float4 q4 = *(const float4*)(qp + g * 4);
    a0 += q4.x * kp[(g * 4 + 0) * 81] + q4.y * kp[(g * 4 + 1) * 81] +
          q4.z * kp[(g * 4 + 2) * 81] + q4.w * kp[(g * 4 + 3) * 81];
  }
#pragma unroll
  for (int g = 8; g < 16; ++g) {
    const float4 q4 = *(const float4*)(qp + g * 4);
    a1 += q4.x * kp[(g * 4 + 0) * 81] + q4.y * kp[(g * 4 + 1) * 81] +
          q4.z * kp[(g * 4 + 2) * 81] + q4.w * kp[(g * 4 + 3) * 81];
  }
  // softmax without max-subtraction (logits are O(+-6); f32 has headroom)
  const float e0 = (lane < 49) ? __expf(a0) : 0.f;
  const float e1 = (lane < 49) ? __expf(a1) : 0.f;

  // Z_s = sum_n (Pj+eps)*e per head; combine weights
  const float* spL = &simsL[cell * 9];
  float tv[9];
#pragma unroll
  for (int s = 0; s < 9; ++s) tv[s] = spL[s];
  const float* cpc = &simsL[((i - rstart0) * 10 + (j - cstart0)) * 9];
  float w0 = 0.f, w1 = 0.f;
#pragma unroll
  for (int s = 0; s < 9; ++s) {
    const float Z0 = rl_f(wave_sum63(tv[s] * e0), 63);
    const float Z1 = rl_f(wave_sum63(tv[s] * e1), 63);
    const float pis = cpc[s];
    w0 += tv[s] * (pis * rcp_fast(Z0));
    w1 += tv[s] * (pis * rcp_fast(Z1));
  }
  w0 *= e0;  // wcomb[h0][n=lane]
  w1 *= e1;  // wcomb[h1][n=lane]

  // PV: lane = out channel; b64 global (v0'[ch],v1'[ch]); w via readlane
  const float* vbase =
      qkvb + ((rstart0 + dr) * 96 + cstart0 + dc) * 256 + 128 + 2 * lane;
  float o0 = bp, o1 = 0.f, o2 = 0.f, o3 = 0.f;
#pragma unroll
  for (int r = 0; r < 7; ++r) {
    const float* vrow = vbase + (size_t)r * (96 * 256);
#pragma unroll
    for (int c = 0; c < 7; ++c) {
      const int n = r * 7 + c;
      const float2 v2 = *(const float2*)(vrow + c * 256);
      const float wa = rl_f(w0, n);
      const float wb = rl_f(w1, n);
      if (n & 1) { o2 += wa * v2.x; o3 += wb * v2.y; }
      else       { o0 += wa * v2.x; o1 += wb * v2.y; }
    }
  }
  out[(bb * 64 + lane) * HWN + i * 96 + j] = (o0 + o2) + (o1 + o3);
}

extern "C" void kernel_launch(void* const* d_in, const int* in_sizes, int n_in,
                              void* d_out, int out_size, void* d_ws, size_t ws_size,
                              hipStream_t stream) {
  const float* x      = (const float*)d_in[0];
  const float* sims   = (const float*)d_in[1];
  const float* w_qk   = (const float*)d_in[2];
  const float* w_v    = (const float*)d_in[3];
  const float* w_proj = (const float*)d_in[4];
  const float* b_proj = (const float*)d_in[5];
  float* outp  = (float*)d_out;
  float* qkv   = (float*)d_ws;                 // 18432*256*4 = 18.9 MB
  float* w_vpI = qkv + (size_t)18432 * 256;    // 8192 floats

  prep_kernel<<<dim3(16), dim3(256), 0, stream>>>(w_v, w_proj, w_vpI);
  qkv_proj_kernel<<<dim3(1152), dim3(256), 0, stream>>>(x, w_qk, w_vpI, qkv);
  attn_fused_kernel<<<dim3(2304), dim3(512), 0, stream>>>(qkv, sims, b_proj,
                                                          outp);
}